// Round 5
// baseline (8465.424 us; speedup 1.0000x reference)
//
#include <hip/hip_runtime.h>

typedef __attribute__((ext_vector_type(8))) _Float16 f16x8;
typedef __attribute__((ext_vector_type(4))) float f32x4;
typedef unsigned long long ull;

#define T_STEPS 1024
#define BATCH   128
#define FDIM    128
#define UDIM    256
#define GCOLS   1024   // 4*U
#define ROWS    16     // batch rows per workgroup (= batch group)
#define HWPR    128    // 64-bit h words per row (256 fp16 / 2)

// Geometry: 64 WGs = 8 batch-groups x 8 u-slices. 4 waves/WG; each wave owns
// ALL 4 gates for 8 u-columns -> gate math is intra-wave, no LDS, no barriers.
// h exchange: tagged 64-bit words {lo32: 2 fp16, hi32: step tag} in L3 via
// relaxed agent-scope atomics; readers poll exactly the words they consume.

__global__ __launch_bounds__(256, 1)
void lstm_scan_kernel(const float* __restrict__ xg, const float* __restrict__ Wg,
                      const float* __restrict__ Rg, const float* __restrict__ bg_,
                      float* __restrict__ outg, ull* __restrict__ hbuf)
{
    const int tid  = threadIdx.x;
    const int lane = tid & 63;
    const int wv   = tid >> 6;          // wave 0..3
    const int bgi  = blockIdx.x & 7;    // batch group
    const int ngi  = blockIdx.x >> 3;   // u-slice group
    const int r0   = bgi * ROWS;
    const int u0   = ngi * 32;
    const int lj   = lane & 15;         // MFMA m/n index
    const int lg   = lane >> 4;         // MFMA k-group
    const int hb   = lj >> 3;           // half: 0 -> gate{i,g} owner, rows lg*4+{0,1}
    const int uc   = u0 + wv * 8 + (lj & 7);   // this lane's u column (global 0..255)

    // ---- one-time: B fragments (W;R combined, fp16) in registers ----
    // n-tile nt covers gates {2nt, 2nt+1}: lane col = gate (nt*2+hb), ucol uc.
    f16x8 bfr[2][12];
#pragma unroll
    for (int nt = 0; nt < 2; ++nt) {
        const int col = (nt * 2 + hb) * 256 + uc;
#pragma unroll
        for (int ks = 0; ks < 12; ++ks) {
            f16x8 v;
#pragma unroll
            for (int i = 0; i < 8; ++i) {
                const int k = ks * 32 + lg * 8 + i;
                const float wgt = (k < FDIM) ? Wg[k * GCOLS + col]
                                             : Rg[(k - FDIM) * GCOLS + col];
                v[i] = (_Float16)wgt;
            }
            bfr[nt][ks] = v;
        }
    }

    const float b_i = bg_[uc];
    const float b_f = bg_[256 + uc];
    const float b_g = bg_[512 + uc];
    const float b_o = bg_[768 + uc];

    const int row0 = lg * 4 + hb * 2;   // first of this lane's 2 output rows
    float cc0 = 0.f, cc1 = 0.f;         // cell state

    const size_t hrow = (size_t)(r0 + lj) * HWPR + lg * 4;       // word offset in one buffer
    const float* const xrow = xg + (size_t)(r0 + lj) * T_STEPS * FDIM + lg * 8;

    for (int t = 0; t < T_STEPS; ++t) {
        const int p = t & 1;
        const ull* hp = hbuf + (size_t)p * BATCH * HWPR + hrow;
        const float* xp = xrow + (size_t)t * FDIM;

        // ---- issue x loads FIRST (so consuming them doesn't drain h loads) ----
        f32x4 xlo[4], xhi[4];
#pragma unroll
        for (int ks = 0; ks < 4; ++ks) {
            xlo[ks] = *(const f32x4*)(xp + ks * 32);
            xhi[ks] = *(const f32x4*)(xp + ks * 32 + 4);
        }

        // ---- issue the 32 h-word polls (this lane's exact MFMA operands) ----
        ull hv[32];
#pragma unroll
        for (int ks = 0; ks < 8; ++ks)
#pragma unroll
            for (int j = 0; j < 4; ++j)
                hv[ks * 4 + j] = __hip_atomic_load(hp + ks * 16 + j,
                                    __ATOMIC_RELAXED, __HIP_MEMORY_SCOPE_AGENT);

        // ---- x*W MFMA (independent of h) overlaps the h-load latency ----
        f32x4 a0e = {0,0,0,0}, a0o = {0,0,0,0}, a1e = {0,0,0,0}, a1o = {0,0,0,0};
#pragma unroll
        for (int ks = 0; ks < 4; ++ks) {
            f16x8 a;
#pragma unroll
            for (int i = 0; i < 4; ++i) { a[i] = (_Float16)xlo[ks][i]; a[4 + i] = (_Float16)xhi[ks][i]; }
            if (ks & 1) {
                a0o = __builtin_amdgcn_mfma_f32_16x16x32_f16(a, bfr[0][ks], a0o, 0, 0, 0);
                a1o = __builtin_amdgcn_mfma_f32_16x16x32_f16(a, bfr[1][ks], a1o, 0, 0, 0);
            } else {
                a0e = __builtin_amdgcn_mfma_f32_16x16x32_f16(a, bfr[0][ks], a0e, 0, 0, 0);
                a1e = __builtin_amdgcn_mfma_f32_16x16x32_f16(a, bfr[1][ks], a1e, 0, 0, 0);
            }
        }

        // ---- poll tags (t==0: zeroed buffer, tag 0 matches) ----
        {
            const unsigned tg = (unsigned)t;
            while (true) {
                bool ok = true;
#pragma unroll
                for (int j = 0; j < 32; ++j)
                    ok &= ((unsigned)(hv[j] >> 32) == tg);
                if (__all(ok)) break;
#pragma unroll
                for (int j = 0; j < 32; ++j)
                    hv[j] = __hip_atomic_load(hp + (j >> 2) * 16 + (j & 3),
                                __ATOMIC_RELAXED, __HIP_MEMORY_SCOPE_AGENT);
            }
        }

        // ---- h*R MFMA straight from the polled words (lo32 = 2 fp16) ----
#pragma unroll
        for (int ks = 0; ks < 8; ++ks) {
            f16x8 a;
            unsigned* ap = (unsigned*)&a;
            ap[0] = (unsigned)hv[ks * 4 + 0];
            ap[1] = (unsigned)hv[ks * 4 + 1];
            ap[2] = (unsigned)hv[ks * 4 + 2];
            ap[3] = (unsigned)hv[ks * 4 + 3];
            const int kk = 4 + ks;
            if (kk & 1) {
                a0o = __builtin_amdgcn_mfma_f32_16x16x32_f16(a, bfr[0][kk], a0o, 0, 0, 0);
                a1o = __builtin_amdgcn_mfma_f32_16x16x32_f16(a, bfr[1][kk], a1o, 0, 0, 0);
            } else {
                a0e = __builtin_amdgcn_mfma_f32_16x16x32_f16(a, bfr[0][kk], a0e, 0, 0, 0);
                a1e = __builtin_amdgcn_mfma_f32_16x16x32_f16(a, bfr[1][kk], a1e, 0, 0, 0);
            }
        }
        const f32x4 z0 = a0e + a0o;   // gates 0(i),1(f): own gate = hb ? f : i
        const f32x4 z1 = a1e + a1o;   // gates 2(g),3(o)

        // ---- intra-wave gate exchange: partner lane^8 holds the other gate ----
        float s0[4], s1[4];
#pragma unroll
        for (int e = 0; e < 4; ++e) {
            s0[e] = __shfl_xor(z0[e], 8);
            s1[e] = __shfl_xor(z1[e], 8);
        }
        // this lane finalizes rows row0, row0+1 (acc elements hb*2, hb*2+1)
        float zi0 = hb ? s0[2] : z0[0];
        float zi1 = hb ? s0[3] : z0[1];
        float zf0 = hb ? z0[2] : s0[0];
        float zf1 = hb ? z0[3] : s0[1];
        float zg0 = hb ? s1[2] : z1[0];
        float zg1 = hb ? s1[3] : z1[1];
        float zo0 = hb ? z1[2] : s1[0];
        float zo1 = hb ? z1[3] : s1[1];

        zi0 += b_i; zi1 += b_i; zf0 += b_f; zf1 += b_f;
        zg0 += b_g; zg1 += b_g; zo0 += b_o; zo1 += b_o;

        const float i0 = 1.f / (1.f + __expf(-zi0));
        const float f0 = 1.f / (1.f + __expf(-zf0));
        const float o0 = 1.f / (1.f + __expf(-zo0));
        const float i1 = 1.f / (1.f + __expf(-zi1));
        const float f1 = 1.f / (1.f + __expf(-zf1));
        const float o1 = 1.f / (1.f + __expf(-zo1));
        cc0 = f0 * cc0 + i0 * zg0;     // g is LINEAR (activation=None)
        cc1 = f1 * cc1 + i1 * zg1;
        const float h0 = o0 * cc0;     // h = o * c (no tanh on cell)
        const float h1 = o1 * cc1;

        if (t == T_STEPS - 1) {
            float* op = outg + (size_t)(r0 + row0) * UDIM + uc;
            op[0]    = tanhf(h0);      // post-hoc tanh on last h
            op[UDIM] = tanhf(h1);
        } else {
            // pack neighbor ucol (lane^1) and publish tagged words (even lanes)
            const float n0 = __shfl_xor(h0, 1);
            const float n1 = __shfl_xor(h1, 1);
            if (!(lj & 1)) {
                union { _Float16 h[2]; unsigned lo; } pa, pb;
                pa.h[0] = (_Float16)h0; pa.h[1] = (_Float16)n0;
                pb.h[0] = (_Float16)h1; pb.h[1] = (_Float16)n1;
                const ull tagw = (ull)(unsigned)(t + 1) << 32;
                ull* hw = hbuf + (size_t)(p ^ 1) * BATCH * HWPR
                          + (size_t)(r0 + row0) * HWPR + (uc >> 1);
                __hip_atomic_store(hw,        tagw | pa.lo,
                                   __ATOMIC_RELAXED, __HIP_MEMORY_SCOPE_AGENT);
                __hip_atomic_store(hw + HWPR, tagw | pb.lo,
                                   __ATOMIC_RELAXED, __HIP_MEMORY_SCOPE_AGENT);
            }
        }
    }
}

extern "C" void kernel_launch(void* const* d_in, const int* in_sizes, int n_in,
                              void* d_out, int out_size, void* d_ws, size_t ws_size,
                              hipStream_t stream) {
    const float* x = (const float*)d_in[0];   // [128,1024,128]
    const float* W = (const float*)d_in[1];   // [128,1024]
    const float* R = (const float*)d_in[2];   // [256,1024]
    const float* b = (const float*)d_in[3];   // [1024]
    float* out = (float*)d_out;               // [128,256]

    ull* hbuf = (ull*)d_ws;                   // [2][128][128] tagged words

    // zero tags every launch (tag 0 == "h ready for step 0", h == 0);
    // also resets stale tags from the previous timed replay.
    const size_t clr = (size_t)2 * BATCH * HWPR * sizeof(ull);
    hipMemsetAsync(d_ws, 0, clr, stream);

    hipLaunchKernelGGL(lstm_scan_kernel, dim3(64), dim3(256), 0, stream,
                       x, W, R, b, out, hbuf);
}